// Round 14
// baseline (193.115 us; speedup 1.0000x reference)
//
#include <hip/hip_runtime.h>

// LocallyLowRank: N=4, A=16, H=W=384, 8x8 blocks stride 4 -> NB=95.
// out[p,:] = x[p,:] * S_p / w_p,  S_p = sum_{b covering p} Phi_b,
// Phi_b = V max(1-2/sigma,0)/1 V^T from G = m_b^T m_b (one-sided Jacobi).
//
// R20: in-lane ILP -- 8 matrices per wave (was 4). Each lane runs TWO
// independent Jacobi chains (matrices g and g+4); the two serial
// rotation chains interleave and fill each other's trans-latency stalls
// (llr_phi was VALUBusy 72% / occupancy 54% -> dependency-stall bound).
// LDS 20480->40960B (4 blocks/CU = 16 waves/CU ~= current 17 average).
// Tail wave (id>=NMAT_) computes on zeros: gam=0 -> identity rotations,
// rho=0; stores guarded. Jacobi math/exchanges per matrix unchanged.
// HARD RULES: (a) never feed ds_swizzle results into INLINE-ASM consumers
// (builtin consumers safe -- R7/R8/R18); (b) never feed MFMA results into
// inline-asm consumers (plain store only); (c) NSWEEP_=4 minimum (R14);
// (d) out2 stages S gather first, x loads in the barrier shadow (R17).

typedef __attribute__((ext_vector_type(2))) float v2f;
typedef __attribute__((ext_vector_type(4))) float f32x4;
typedef __attribute__((ext_vector_type(8))) short s16x8;
typedef union { float4 f4; v2f v2[2]; } f4v2;

#define N_      4
#define A_      16
#define H_      384
#define W_      384
#define PLANE_  (H_*W_)       // 147456
#define NB_     95
#define NBB_    (NB_*NB_)     // 9025
#define NMAT_   (N_*NBB_)     // 36100
#define NWAVE8_ ((NMAT_ + 7) / 8)   // 4513 (tail wave: 4 real + 4 zero)
#define NSWEEP_ 4
#define PHI_BYTES_ ((size_t)NMAT_ * 256 * 4)   // 36.97 MB

// ---- packed fp32 ops, forced (VOP3P) -- used ONLY where inputs are
// compiler-visible plain values (Phase 2, out2) ------------------------------
__device__ __forceinline__ v2f pk_fma(v2f a, v2f b, v2f c) {
    v2f d; asm("v_pk_fma_f32 %0, %1, %2, %3" : "=v"(d) : "v"(a), "v"(b), "v"(c));
    return d;
}
__device__ __forceinline__ v2f pk_mul(v2f a, v2f b) {
    v2f d; asm("v_pk_mul_f32 %0, %1, %2" : "=v"(d) : "v"(a), "v"(b));
    return d;
}

// ---- bf16 pack helpers ------------------------------------------------------
__device__ __forceinline__ unsigned cvtpk_bf16(float a, float b) {
    unsigned d;   // d[15:0]=bf16(a), d[31:16]=bf16(b), RNE
    asm("v_cvt_pk_bf16_f32 %0, %1, %2" : "=v"(d) : "v"(a), "v"(b));
    return d;
}
__device__ __forceinline__ float asf_(unsigned u) {
    union { unsigned u; float f; } x; x.u = u; return x.f;
}
typedef union { s16x8 s8; unsigned u[4]; } frag8;

// split 8 fp32 (two float4) into bf16 hi frag + bf16 lo frag (residual)
__device__ __forceinline__ void split8(const float4 A, const float4 B,
                                       frag8& hi, frag8& lo) {
    hi.u[0] = cvtpk_bf16(A.x, A.y);
    hi.u[1] = cvtpk_bf16(A.z, A.w);
    hi.u[2] = cvtpk_bf16(B.x, B.y);
    hi.u[3] = cvtpk_bf16(B.z, B.w);
    const float l0 = A.x - asf_(hi.u[0] << 16);
    const float l1 = A.y - asf_(hi.u[0] & 0xFFFF0000u);
    const float l2 = A.z - asf_(hi.u[1] << 16);
    const float l3 = A.w - asf_(hi.u[1] & 0xFFFF0000u);
    const float l4 = B.x - asf_(hi.u[2] << 16);
    const float l5 = B.y - asf_(hi.u[2] & 0xFFFF0000u);
    const float l6 = B.z - asf_(hi.u[3] << 16);
    const float l7 = B.w - asf_(hi.u[3] & 0xFFFF0000u);
    lo.u[0] = cvtpk_bf16(l0, l1);
    lo.u[1] = cvtpk_bf16(l2, l3);
    lo.u[2] = cvtpk_bf16(l4, l5);
    lo.u[3] = cvtpk_bf16(l6, l7);
}

// ---- single DPP16 primitive ------------------------------------------------
template<int CTRL>
__device__ __forceinline__ float dpp16(float v) {
    union { float f; int i; } u; u.f = v;
    u.i = __builtin_amdgcn_mov_dpp(u.i, CTRL, 0xF, 0xF, true);
    return u.f;
}

#define QP1_ 0xB1   // quad_perm [1,0,3,2] = xor 1
#define QP2_ 0x4E   // quad_perm [2,3,0,1] = xor 2
#define QP3_ 0x1B   // quad_perm [3,2,1,0] = xor 3
#define HM_  0x141  // row_half_mirror = xor 7
#define FM_  0x140  // row_mirror      = xor 15
#define R8_  0x128  // row_ror:8       = xor 8

// ---- 16-lane xor exchange: 1-DPP masks on VALU; 2-DPP masks via single
// ds_swizzle on the LDS pipe. Consumers are builtins -> compiler inserts
// lgkmcnt (R7/R8/R18-proven-safe combination). ------------------------------
template<int M>
__device__ __forceinline__ float lane_xor16(float v) {
    if constexpr (M == 1)       return dpp16<QP1_>(v);
    else if constexpr (M == 2)  return dpp16<QP2_>(v);
    else if constexpr (M == 3)  return dpp16<QP3_>(v);
    else if constexpr (M == 7)  return dpp16<HM_>(v);
    else if constexpr (M == 8)  return dpp16<R8_>(v);
    else if constexpr (M == 15) return dpp16<FM_>(v);
    else {
        // BitMode: new_lane = (lane & 0x1F) ^ M. One LDS-pipe inst vs
        // two chained VALU DPPs.
        union { float f; int i; } u; u.f = v;
        u.i = __builtin_amdgcn_ds_swizzle(u.i, (M << 10) | 0x1F);
        return u.f;
    }
}

// One Jacobi rotation round on TWO independent matrices' packed column
// state (wA, wB; 16 floats each). The two serial rotation chains are
// independent -> instruction-level interleave fills trans-latency stalls.
// R15 zeta-form math; all ops compiler-visible (no inline asm).
template<int M>
__device__ __forceinline__ void jacobi_round2(v2f wA[8], v2f wB[8],
                                              float& nrmA, float& nrmB,
                                              const int j) {
    v2f pA[8], pB[8];
    #pragma unroll
    for (int i = 0; i < 8; ++i) {
        pA[i][0] = lane_xor16<M>(wA[i][0]);
        pA[i][1] = lane_xor16<M>(wA[i][1]);
        pB[i][0] = lane_xor16<M>(wB[i][0]);
        pB[i][1] = lane_xor16<M>(wB[i][1]);
    }
    const float pnA = lane_xor16<M>(nrmA);
    const float pnB = lane_xor16<M>(nrmB);

    v2f a0 = wA[0]*pA[0], a1 = wA[1]*pA[1];
    v2f b0 = wB[0]*pB[0], b1 = wB[1]*pB[1];
    #pragma unroll
    for (int i = 2; i < 8; i += 2) {
        a0 = __builtin_elementwise_fma(wA[i],   pA[i],   a0);
        a1 = __builtin_elementwise_fma(wA[i+1], pA[i+1], a1);
        b0 = __builtin_elementwise_fma(wB[i],   pB[i],   b0);
        b1 = __builtin_elementwise_fma(wB[i+1], pB[i+1], b1);
    }
    const v2f dsA = a0 + a1;
    const v2f dsB = b0 + b1;
    const float gamA = dsA[0] + dsA[1];
    const float gamB = dsB[0] + dsB[1];

    const bool low = ((j ^ M) > j);         // canonical order -> identical c,s

    // chain A
    const float naA = low ? nrmA : pnA;
    const float nbA = low ? pnA  : nrmA;
    const float thrA = 1e-12f * (naA + nbA);
    const bool  rotA = fabsf(gamA) > thrA;
    const float gsA  = rotA ? gamA : 1.f;
    const float zA = (nbA - naA) * (0.5f * __builtin_amdgcn_rcpf(gsA));
    const float rtA = __builtin_amdgcn_rcpf(
                          fabsf(zA) +
                          __builtin_amdgcn_sqrtf(__builtin_fmaf(zA, zA, 1.f)));
    float tA = copysignf(rtA, zA);
    float cA = __builtin_amdgcn_rsqf(__builtin_fmaf(tA, tA, 1.f));
    float svA = cA * tA;
    if (!rotA) { cA = 1.f; svA = 0.f; tA = 0.f; }

    // chain B (independent -> interleaves with A)
    const float naB = low ? nrmB : pnB;
    const float nbB = low ? pnB  : nrmB;
    const float thrB = 1e-12f * (naB + nbB);
    const bool  rotB = fabsf(gamB) > thrB;
    const float gsB  = rotB ? gamB : 1.f;
    const float zB = (nbB - naB) * (0.5f * __builtin_amdgcn_rcpf(gsB));
    const float rtB = __builtin_amdgcn_rcpf(
                          fabsf(zB) +
                          __builtin_amdgcn_sqrtf(__builtin_fmaf(zB, zB, 1.f)));
    float tB = copysignf(rtB, zB);
    float cB = __builtin_amdgcn_rsqf(__builtin_fmaf(tB, tB, 1.f));
    float svB = cB * tB;
    if (!rotB) { cB = 1.f; svB = 0.f; tB = 0.f; }

    const float ssA = low ? -svA : svA;
    const float ssB = low ? -svB : svB;
    const v2f cA2 = {cA, cA}, sA2 = {ssA, ssA};
    const v2f cB2 = {cB, cB}, sB2 = {ssB, ssB};
    #pragma unroll
    for (int i = 0; i < 8; ++i) {
        wA[i] = __builtin_elementwise_fma(cA2, wA[i], sA2*pA[i]);
        wB[i] = __builtin_elementwise_fma(cB2, wB[i], sB2*pB[i]);
    }

    // Rutishauser norm updates
    nrmA = __builtin_fmaf(low ? -tA : tA, gamA, nrmA);
    nrmB = __builtin_fmaf(low ? -tB : tB, gamB, nrmB);
}

// Shared phases 1-4: Gram (MFMA) + dual-chain Jacobi + Phi (MFMA).
// One wave, 8 matrices, 16 lanes/(matrix pair). No block barriers.
__device__ __forceinline__ void gram_jacobi_phi(
        const float* __restrict__ x, const int wid, const int warp,
        const int lane, float Gl[4][8][320]) {
    const int g   = lane >> 4;
    const int j   = lane & 15;
    const int kq4 = g * 4;

    // -------- Phase 1: Gram via MFMA, 8 matrices (tail -> zero slab) --------
    // MFMA results consumed ONLY by plain stores (hard rule b).
    #pragma unroll
    for (int s = 0; s < 8; ++s) {
        const int id = wid * 8 + s;
        if (id < NMAT_) {
            const int n   = id / NBB_;
            const int rem = id % NBB_;
            const int bi  = rem / NB_;
            const int bj  = rem % NB_;
            const float* bp = x + (size_t)n * (A_ * PLANE_) + (size_t)j * PLANE_
                                + (bi*4 + g) * W_ + bj*4;

            const float4 va = *(const float4*)(bp);
            const float4 vb = *(const float4*)(bp + 4);
            const float4 vc = *(const float4*)(bp + 4*W_);
            const float4 vd = *(const float4*)(bp + 4*W_ + 4);

            frag8 hi0, lo0, hi1, lo1;
            split8(va, vb, hi0, lo0);
            split8(vc, vd, hi1, lo1);

            f32x4 C = {0.f, 0.f, 0.f, 0.f};
            C = __builtin_amdgcn_mfma_f32_16x16x32_bf16(lo0.s8, hi0.s8, C, 0, 0, 0);
            C = __builtin_amdgcn_mfma_f32_16x16x32_bf16(hi0.s8, lo0.s8, C, 0, 0, 0);
            C = __builtin_amdgcn_mfma_f32_16x16x32_bf16(hi0.s8, hi0.s8, C, 0, 0, 0);
            C = __builtin_amdgcn_mfma_f32_16x16x32_bf16(lo1.s8, hi1.s8, C, 0, 0, 0);
            C = __builtin_amdgcn_mfma_f32_16x16x32_bf16(hi1.s8, lo1.s8, C, 0, 0, 0);
            C = __builtin_amdgcn_mfma_f32_16x16x32_bf16(hi1.s8, hi1.s8, C, 0, 0, 0);

            // C lane layout: col=lane&15 (=j), row=4*(lane>>4)+r (=kq4+r).
            *(float4*)&Gl[warp][s][j*20 + kq4] = make_float4(C[0], C[1], C[2], C[3]);
        } else {
            *(float4*)&Gl[warp][s][j*20 + kq4] = make_float4(0.f, 0.f, 0.f, 0.f);
        }
    }
    __builtin_amdgcn_wave_barrier();

    // -------- Phase 2: TWO columns into registers (matrices g and g+4) ------
    v2f wA[8], wB[8];
    {
        f4v2 t0, t1, t2, t3;
        t0.f4 = *(const float4*)&Gl[warp][g][j*20 + 0];
        t1.f4 = *(const float4*)&Gl[warp][g][j*20 + 4];
        t2.f4 = *(const float4*)&Gl[warp][g][j*20 + 8];
        t3.f4 = *(const float4*)&Gl[warp][g][j*20 + 12];
        wA[0]=t0.v2[0]; wA[1]=t0.v2[1]; wA[2]=t1.v2[0]; wA[3]=t1.v2[1];
        wA[4]=t2.v2[0]; wA[5]=t2.v2[1]; wA[6]=t3.v2[0]; wA[7]=t3.v2[1];
        t0.f4 = *(const float4*)&Gl[warp][g+4][j*20 + 0];
        t1.f4 = *(const float4*)&Gl[warp][g+4][j*20 + 4];
        t2.f4 = *(const float4*)&Gl[warp][g+4][j*20 + 8];
        t3.f4 = *(const float4*)&Gl[warp][g+4][j*20 + 12];
        wB[0]=t0.v2[0]; wB[1]=t0.v2[1]; wB[2]=t1.v2[0]; wB[3]=t1.v2[1];
        wB[4]=t2.v2[0]; wB[5]=t2.v2[1]; wB[6]=t3.v2[0]; wB[7]=t3.v2[1];
    }
    float nrmA, nrmB;
    {
        v2f dA = pk_mul(wA[0], wA[0]);
        v2f dB = pk_mul(wB[0], wB[0]);
        #pragma unroll
        for (int i = 1; i < 8; ++i) {
            dA = pk_fma(wA[i], wA[i], dA);
            dB = pk_fma(wB[i], wB[i], dB);
        }
        nrmA = dA[0] + dA[1];
        nrmB = dB[0] + dB[1];
    }

    // -------- Phase 3: dual-chain one-sided Jacobi (4 sweeps REQUIRED) ------
    for (int sweep = 0; sweep < NSWEEP_; ++sweep) {
        jacobi_round2<1>(wA, wB, nrmA, nrmB, j);
        jacobi_round2<2>(wA, wB, nrmA, nrmB, j);
        jacobi_round2<3>(wA, wB, nrmA, nrmB, j);
        jacobi_round2<4>(wA, wB, nrmA, nrmB, j);
        jacobi_round2<5>(wA, wB, nrmA, nrmB, j);
        jacobi_round2<6>(wA, wB, nrmA, nrmB, j);
        jacobi_round2<7>(wA, wB, nrmA, nrmB, j);
        jacobi_round2<8>(wA, wB, nrmA, nrmB, j);
        jacobi_round2<9>(wA, wB, nrmA, nrmB, j);
        jacobi_round2<10>(wA, wB, nrmA, nrmB, j);
        jacobi_round2<11>(wA, wB, nrmA, nrmB, j);
        jacobi_round2<12>(wA, wB, nrmA, nrmB, j);
        jacobi_round2<13>(wA, wB, nrmA, nrmB, j);
        jacobi_round2<14>(wA, wB, nrmA, nrmB, j);
        jacobi_round2<15>(wA, wB, nrmA, nrmB, j);
    }
    {   // exact norms (drift removal)
        v2f dA = pk_mul(wA[0], wA[0]);
        v2f dB = pk_mul(wB[0], wB[0]);
        #pragma unroll
        for (int i = 1; i < 8; ++i) {
            dA = pk_fma(wA[i], wA[i], dA);
            dB = pk_fma(wB[i], wB[i], dB);
        }
        nrmA = dA[0] + dA[1];
        nrmB = dB[0] + dB[1];
    }
    float rhoA = 0.f, rhoB = 0.f;            // max(1-2/sigma,0)/lam^2
    if (nrmA > 16.f) {
        const float lam = __builtin_amdgcn_sqrtf(nrmA);
        rhoA = (1.f - 2.f * __builtin_amdgcn_rsqf(lam)) * __builtin_amdgcn_rcpf(nrmA);
    }
    if (nrmB > 16.f) {
        const float lam = __builtin_amdgcn_sqrtf(nrmB);
        rhoB = (1.f - 2.f * __builtin_amdgcn_rsqf(lam)) * __builtin_amdgcn_rcpf(nrmB);
    }

    __builtin_amdgcn_wave_barrier();
    *(float4*)&Gl[warp][g][j*20 + 0]  = make_float4(wA[0][0], wA[0][1], wA[1][0], wA[1][1]);
    *(float4*)&Gl[warp][g][j*20 + 4]  = make_float4(wA[2][0], wA[2][1], wA[3][0], wA[3][1]);
    *(float4*)&Gl[warp][g][j*20 + 8]  = make_float4(wA[4][0], wA[4][1], wA[5][0], wA[5][1]);
    *(float4*)&Gl[warp][g][j*20 + 12] = make_float4(wA[6][0], wA[6][1], wA[7][0], wA[7][1]);
    Gl[warp][g][j*20 + 16] = rhoA;
    *(float4*)&Gl[warp][g+4][j*20 + 0]  = make_float4(wB[0][0], wB[0][1], wB[1][0], wB[1][1]);
    *(float4*)&Gl[warp][g+4][j*20 + 4]  = make_float4(wB[2][0], wB[2][1], wB[3][0], wB[3][1]);
    *(float4*)&Gl[warp][g+4][j*20 + 8]  = make_float4(wB[4][0], wB[4][1], wB[5][0], wB[5][1]);
    *(float4*)&Gl[warp][g+4][j*20 + 12] = make_float4(wB[6][0], wB[6][1], wB[7][0], wB[7][1]);
    Gl[warp][g+4][j*20 + 16] = rhoB;
    __builtin_amdgcn_wave_barrier();

    // -------- Phase 4 (MFMA): Phi_s = (rho (.) W) W^T, K=16 padded to 32 ----
    // Per-slab: read -> MFMA -> barrier -> write (slab writes only touch the
    // slab just read; iterations are disjoint). MFMA dest -> plain stores.
    {
        const int kg = lane >> 4;
        const int mn = lane & 15;
        #pragma unroll
        for (int s = 0; s < 8; ++s) {
            frag8 Ahi, Alo, Bhi, Blo;
            if (kg < 2) {
                float av[8], bv[8];
                #pragma unroll
                for (int e = 0; e < 8; ++e) {
                    const int k = kg*8 + e;
                    const float wv = Gl[warp][s][k*20 + mn];
                    const float rh = Gl[warp][s][k*20 + 16];
                    bv[e] = wv;
                    av[e] = wv * rh;
                }
                split8(make_float4(av[0],av[1],av[2],av[3]),
                       make_float4(av[4],av[5],av[6],av[7]), Ahi, Alo);
                split8(make_float4(bv[0],bv[1],bv[2],bv[3]),
                       make_float4(bv[4],bv[5],bv[6],bv[7]), Bhi, Blo);
            } else {
                Ahi.u[0]=0u; Ahi.u[1]=0u; Ahi.u[2]=0u; Ahi.u[3]=0u;
                Alo = Ahi; Bhi = Ahi; Blo = Ahi;
            }
            f32x4 C = {0.f, 0.f, 0.f, 0.f};
            C = __builtin_amdgcn_mfma_f32_16x16x32_bf16(Alo.s8, Bhi.s8, C, 0, 0, 0);
            C = __builtin_amdgcn_mfma_f32_16x16x32_bf16(Ahi.s8, Blo.s8, C, 0, 0, 0);
            C = __builtin_amdgcn_mfma_f32_16x16x32_bf16(Ahi.s8, Bhi.s8, C, 0, 0, 0);
            __builtin_amdgcn_wave_barrier();  // slab-s reads done -> overwrite
            #pragma unroll
            for (int r2 = 0; r2 < 4; ++r2)
                Gl[warp][s][(4*kg + r2)*20 + mn] = C[r2];
            __builtin_amdgcn_wave_barrier();
        }
    }
}

// =================== K1: Phi per block -> global ============================
__global__ __launch_bounds__(256, 4)
void llr_phi(const float* __restrict__ x, float* __restrict__ phiG) {
    __shared__ __align__(16) float Gl[4][8][320];   // 40960 B -> 4 blocks/CU
    const int warp = threadIdx.x >> 6;
    const int lane = threadIdx.x & 63;

    // bijective XCD-chunked swizzle: nwg=1129, q=141, r=1.
    const int xcd = blockIdx.x & 7, idx = blockIdx.x >> 3;
    const int wg  = (xcd == 0 ? idx : 142 + (xcd - 1) * 141 + idx);
    const int wid = wg * 4 + warp;
    if (wid >= NWAVE8_) return;

    gram_jacobi_phi(x, wid, warp, lane, Gl);

    // Phi symmetric -> column j IS row j: 64B contiguous store per lane.
    // Two matrices per lane (slabs g and g+4), tail-guarded.
    const int g = lane >> 4, j = lane & 15;
    #pragma unroll
    for (int h = 0; h < 2; ++h) {
        const int s  = g + 4*h;
        const int id = wid*8 + s;
        if (id < NMAT_) {
            float* pb = phiG + (size_t)id * 256 + j * 16;
            const float4 p0 = *(const float4*)&Gl[warp][s][j*20 + 0];
            const float4 p1 = *(const float4*)&Gl[warp][s][j*20 + 4];
            const float4 p2 = *(const float4*)&Gl[warp][s][j*20 + 8];
            const float4 p3 = *(const float4*)&Gl[warp][s][j*20 + 12];
            *(float4*)&pb[0]  = p0;  *(float4*)&pb[4]  = p1;
            *(float4*)&pb[8]  = p2;  *(float4*)&pb[12] = p3;
        }
    }
}

// =================== K2: out = x * (sum Phi)/w, tiled 8x32 px ===============
__global__ __launch_bounds__(256, 8)
void llr_out2(const float* __restrict__ x, const float* __restrict__ phiG,
              float* __restrict__ out) {
    __shared__ __align__(16) float Sl[16][260];   // stride 260: conflict-free reads

    // bijective XCD-chunked swizzle: nwg=2304 (divisible by 8), q=288.
    const int b  = (blockIdx.x & 7) * 288 + (blockIdx.x >> 3);
    const int n  = b / 576;
    const int tt = b % 576;
    const int tr = tt / 12, tc = tt % 12;
    const int r0 = tr*8, c0 = tc*32;
    const int cr0 = tr*2, cc0 = tc*8;   // global cell coords of tile origin

    const int r = threadIdx.x >> 5;          // 0..7 (wave = 2 rows, same cell-row)
    const int c = threadIdx.x & 31;          // 0..31 -> coalesced
    const int lcc = ((r >> 2) << 3) + (c >> 2);
    const size_t sb = (size_t)n * (A_*PLANE_) + (size_t)(r0 + r) * W_ + (c0 + c);

    // -------- stage S FIRST (critical-path gather issued first, rule d): ----
    // branch-free clamped 4-load sum * 0.25 (== weighted sum exactly).
    {
        const int lc = threadIdx.x >> 4;         // local cell 0..15
        const int fo = (threadIdx.x & 15) * 4;   // float offset 0..60
        const int ci = cr0 + (lc >> 3);
        const int cj = cc0 + (lc & 7);
        const int bi0 = max(ci - 1, 0), bi1 = min(ci, NB_ - 1);
        const int bj0 = max(cj - 1, 0), bj1 = min(cj, NB_ - 1);
        const size_t r00 = ((size_t)(n*NBB_ + bi0*NB_ + bj0))*256;
        const size_t r01 = ((size_t)(n*NBB_ + bi0*NB_ + bj1))*256;
        const size_t r10 = ((size_t)(n*NBB_ + bi1*NB_ + bj0))*256;
        const size_t r11 = ((size_t)(n*NBB_ + bi1*NB_ + bj1))*256;
        #pragma unroll
        for (int it = 0; it < 4; ++it) {
            const int off = fo + it*64;
            const float4 a  = *(const float4*)&phiG[r00 + off];
            const float4 bq = *(const float4*)&phiG[r01 + off];
            const float4 cq = *(const float4*)&phiG[r10 + off];
            const float4 d  = *(const float4*)&phiG[r11 + off];
            float4 s;
            s.x = (a.x + bq.x + cq.x + d.x) * 0.25f;
            s.y = (a.y + bq.y + cq.y + d.y) * 0.25f;
            s.z = (a.z + bq.z + cq.z + d.z) * 0.25f;
            s.w = (a.w + bq.w + cq.w + d.w) * 0.25f;
            *(float4*)&Sl[lc][off] = s;
        }
    }

    // -------- x loads: issued AFTER the gather (already in flight), BEFORE
    // the barrier -- their latency hides under the barrier wait. ------------
    float xk[16];
    #pragma unroll
    for (int k = 0; k < 16; ++k) xk[k] = x[sb + (size_t)k * PLANE_];

    __syncthreads();

    // -------- compute: thread = 1 pixel, all 16 channels --------------------
    v2f acc[8];
    #pragma unroll
    for (int i = 0; i < 8; ++i) acc[i] = (v2f){0.f, 0.f};
    #pragma unroll
    for (int k = 0; k < 16; ++k) {
        const v2f xv = {xk[k], xk[k]};
        f4v2 s0, s1, s2, s3;
        s0.f4 = *(const float4*)&Sl[lcc][k*16 + 0];
        s1.f4 = *(const float4*)&Sl[lcc][k*16 + 4];
        s2.f4 = *(const float4*)&Sl[lcc][k*16 + 8];
        s3.f4 = *(const float4*)&Sl[lcc][k*16 + 12];
        acc[0] = pk_fma(xv, s0.v2[0], acc[0]);
        acc[1] = pk_fma(xv, s0.v2[1], acc[1]);
        acc[2] = pk_fma(xv, s1.v2[0], acc[2]);
        acc[3] = pk_fma(xv, s1.v2[1], acc[3]);
        acc[4] = pk_fma(xv, s2.v2[0], acc[4]);
        acc[5] = pk_fma(xv, s2.v2[1], acc[5]);
        acc[6] = pk_fma(xv, s3.v2[0], acc[6]);
        acc[7] = pk_fma(xv, s3.v2[1], acc[7]);
    }
    #pragma unroll
    for (int i = 0; i < 8; ++i) {
        out[sb + (size_t)(2*i)     * PLANE_] = acc[i][0];
        out[sb + (size_t)(2*i + 1) * PLANE_] = acc[i][1];
    }
}

// =================== Fallback (ws too small): fused + atomics ===============
__global__ __launch_bounds__(256, 4)
void llr_fused(const float* __restrict__ x, float* __restrict__ out) {
    __shared__ __align__(16) float Gl[4][8][320];
    const int warp = threadIdx.x >> 6;
    const int lane = threadIdx.x & 63;
    const int wid  = blockIdx.x * 4 + warp;
    if (wid >= NWAVE8_) return;

    gram_jacobi_phi(x, wid, warp, lane, Gl);

    const int pr = lane >> 3, pc = lane & 7;
    for (int s = 0; s < 8; ++s) {
        const int id = wid*8 + s;
        if (id >= NMAT_) break;
        const int n = id / NBB_, rem = id % NBB_;
        const int bi = rem / NB_, bj = rem % NB_;
        const int base = n*(A_*PLANE_) + (bi*4+pr)*W_ + (bj*4+pc);
        float mr[16];
        #pragma unroll
        for (int a = 0; a < 16; ++a) mr[a] = x[base + a*PLANE_];
        float o[16];
        #pragma unroll
        for (int a = 0; a < 16; ++a) o[a] = 0.f;
        #pragma unroll
        for (int k = 0; k < 16; ++k) {
            const float mk = mr[k];
            const float4 f0 = *(const float4*)&Gl[warp][s][k*20 + 0];
            const float4 f1 = *(const float4*)&Gl[warp][s][k*20 + 4];
            const float4 f2 = *(const float4*)&Gl[warp][s][k*20 + 8];
            const float4 f3 = *(const float4*)&Gl[warp][s][k*20 + 12];
            o[0]+=mk*f0.x;  o[1]+=mk*f0.y;  o[2]+=mk*f0.z;  o[3]+=mk*f0.w;
            o[4]+=mk*f1.x;  o[5]+=mk*f1.y;  o[6]+=mk*f1.z;  o[7]+=mk*f1.w;
            o[8]+=mk*f2.x;  o[9]+=mk*f2.y;  o[10]+=mk*f2.z; o[11]+=mk*f2.w;
            o[12]+=mk*f3.x; o[13]+=mk*f3.y; o[14]+=mk*f3.z; o[15]+=mk*f3.w;
        }
        #pragma unroll
        for (int a = 0; a < 16; ++a)
            unsafeAtomicAdd(&out[base + a*PLANE_], o[a]);
    }
}

__global__ __launch_bounds__(256)
void llr_div(float* __restrict__ out, const float* __restrict__ bw) {
    const int i = (blockIdx.x * 256 + threadIdx.x) * 4;
    float4 o = *(float4*)&out[i];
    const float4 bv = *(const float4*)&bw[i % PLANE_];
    o.x /= bv.x; o.y /= bv.y; o.z /= bv.z; o.w /= bv.w;
    *(float4*)&out[i] = o;
}

extern "C" void kernel_launch(void* const* d_in, const int* in_sizes, int n_in,
                              void* d_out, int out_size, void* d_ws, size_t ws_size,
                              hipStream_t stream) {
    (void)in_sizes; (void)n_in;
    const float* x  = (const float*)d_in[0];
    const float* bw = (const float*)d_in[1];
    float* out = (float*)d_out;

    if (ws_size >= PHI_BYTES_) {
        float* phiG = (float*)d_ws;
        hipLaunchKernelGGL(llr_phi,  dim3((NWAVE8_ + 3) / 4), dim3(256), 0, stream, x, phiG);
        hipLaunchKernelGGL(llr_out2, dim3(4 * 48 * 12),       dim3(256), 0, stream, x, phiG, out);
    } else {
        hipMemsetAsync(out, 0, (size_t)out_size * sizeof(float), stream);
        hipLaunchKernelGGL(llr_fused, dim3((NWAVE8_ + 3) / 4), dim3(256), 0, stream, x, out);
        hipLaunchKernelGGL(llr_div, dim3((N_*A_*PLANE_) / (256*4)), dim3(256), 0, stream, out, bw);
    }
}

// Round 15
// 171.874 us; speedup vs baseline: 1.1236x; 1.1236x over previous
//
#include <hip/hip_runtime.h>

// LocallyLowRank: N=4, A=16, H=W=384, 8x8 blocks stride 4 -> NB=95.
// out[p,:] = x[p,:] * S_p / w_p,  S_p = sum_{b covering p} Phi_b,
// Phi_b = V max(1-2/sigma,0)/1 V^T from G = m_b^T m_b (one-sided Jacobi).
//
// R21: exact revert to R19 (173.7 us, best verified). R20 post-mortem:
// 8-matrices/wave dual-chain ILP REGRESSED (llr_phi 95->133.5): occupancy
// 54->34% (40KB LDS + VGPR52 + tail imbalance), VALUBusy 72->46% -- TLP
// lost > ILP gained. RULE (e): never trade occupancy for in-lane ILP when
// VALUBusy >= ~70%; wave-level parallelism was already hiding latency.
// HARD RULES: (a) never feed ds_swizzle results into INLINE-ASM consumers
// (builtin consumers safe -- R7/R8/R18); (b) never feed MFMA results into
// inline-asm consumers (plain store only); (c) NSWEEP_=4 minimum (R14);
// (d) out2 stages S gather first, x loads in the barrier shadow (R17);
// (e) no occupancy-for-ILP trades at high VALUBusy (R20).

typedef __attribute__((ext_vector_type(2))) float v2f;
typedef __attribute__((ext_vector_type(4))) float f32x4;
typedef __attribute__((ext_vector_type(8))) short s16x8;
typedef union { float4 f4; v2f v2[2]; } f4v2;

#define N_      4
#define A_      16
#define H_      384
#define W_      384
#define PLANE_  (H_*W_)       // 147456
#define NB_     95
#define NBB_    (NB_*NB_)     // 9025
#define NMAT_   (N_*NBB_)     // 36100
#define NWAVE_  ((NMAT_ + 3) / 4)   // 9025
#define NSWEEP_ 4
#define PHI_BYTES_ ((size_t)NMAT_ * 256 * 4)   // 36.97 MB

// ---- packed fp32 ops, forced (VOP3P) -- used ONLY where inputs are
// compiler-visible plain values (Phase 2, out2) ------------------------------
__device__ __forceinline__ v2f pk_fma(v2f a, v2f b, v2f c) {
    v2f d; asm("v_pk_fma_f32 %0, %1, %2, %3" : "=v"(d) : "v"(a), "v"(b), "v"(c));
    return d;
}
__device__ __forceinline__ v2f pk_mul(v2f a, v2f b) {
    v2f d; asm("v_pk_mul_f32 %0, %1, %2" : "=v"(d) : "v"(a), "v"(b));
    return d;
}

// ---- bf16 pack helpers ------------------------------------------------------
__device__ __forceinline__ unsigned cvtpk_bf16(float a, float b) {
    unsigned d;   // d[15:0]=bf16(a), d[31:16]=bf16(b), RNE
    asm("v_cvt_pk_bf16_f32 %0, %1, %2" : "=v"(d) : "v"(a), "v"(b));
    return d;
}
__device__ __forceinline__ float asf_(unsigned u) {
    union { unsigned u; float f; } x; x.u = u; return x.f;
}
typedef union { s16x8 s8; unsigned u[4]; } frag8;

// split 8 fp32 (two float4) into bf16 hi frag + bf16 lo frag (residual)
__device__ __forceinline__ void split8(const float4 A, const float4 B,
                                       frag8& hi, frag8& lo) {
    hi.u[0] = cvtpk_bf16(A.x, A.y);
    hi.u[1] = cvtpk_bf16(A.z, A.w);
    hi.u[2] = cvtpk_bf16(B.x, B.y);
    hi.u[3] = cvtpk_bf16(B.z, B.w);
    const float l0 = A.x - asf_(hi.u[0] << 16);
    const float l1 = A.y - asf_(hi.u[0] & 0xFFFF0000u);
    const float l2 = A.z - asf_(hi.u[1] << 16);
    const float l3 = A.w - asf_(hi.u[1] & 0xFFFF0000u);
    const float l4 = B.x - asf_(hi.u[2] << 16);
    const float l5 = B.y - asf_(hi.u[2] & 0xFFFF0000u);
    const float l6 = B.z - asf_(hi.u[3] << 16);
    const float l7 = B.w - asf_(hi.u[3] & 0xFFFF0000u);
    lo.u[0] = cvtpk_bf16(l0, l1);
    lo.u[1] = cvtpk_bf16(l2, l3);
    lo.u[2] = cvtpk_bf16(l4, l5);
    lo.u[3] = cvtpk_bf16(l6, l7);
}

// ---- single DPP16 primitive ------------------------------------------------
template<int CTRL>
__device__ __forceinline__ float dpp16(float v) {
    union { float f; int i; } u; u.f = v;
    u.i = __builtin_amdgcn_mov_dpp(u.i, CTRL, 0xF, 0xF, true);
    return u.f;
}

#define QP1_ 0xB1   // quad_perm [1,0,3,2] = xor 1
#define QP2_ 0x4E   // quad_perm [2,3,0,1] = xor 2
#define QP3_ 0x1B   // quad_perm [3,2,1,0] = xor 3
#define HM_  0x141  // row_half_mirror = xor 7
#define FM_  0x140  // row_mirror      = xor 15
#define R8_  0x128  // row_ror:8       = xor 8

// ---- 16-lane xor exchange: 1-DPP masks on VALU; 2-DPP masks via single
// ds_swizzle on the LDS pipe. Consumers in jacobi_round are builtins ->
// compiler inserts lgkmcnt (R7/R8/R18-proven-safe combination). -------------
template<int M>
__device__ __forceinline__ float lane_xor16(float v) {
    if constexpr (M == 1)       return dpp16<QP1_>(v);
    else if constexpr (M == 2)  return dpp16<QP2_>(v);
    else if constexpr (M == 3)  return dpp16<QP3_>(v);
    else if constexpr (M == 7)  return dpp16<HM_>(v);
    else if constexpr (M == 8)  return dpp16<R8_>(v);
    else if constexpr (M == 15) return dpp16<FM_>(v);
    else {
        // BitMode: new_lane = (lane & 0x1F) ^ M. One LDS-pipe inst vs
        // two chained VALU DPPs.
        union { float f; int i; } u; u.f = v;
        u.i = __builtin_amdgcn_ds_swizzle(u.i, (M << 10) | 0x1F);
        return u.f;
    }
}

// One Jacobi rotation round on packed column state w[8] (=16 floats).
// R15 zeta-form rotation math. ALL ops compiler-visible (no inline asm):
// safe with ds_swizzle exchanges (R18-proven).
template<int M>
__device__ __forceinline__ void jacobi_round(v2f w[8], float& nrm, const int j) {
    v2f pw[8];
    #pragma unroll
    for (int i = 0; i < 8; ++i) {
        pw[i][0] = lane_xor16<M>(w[i][0]);
        pw[i][1] = lane_xor16<M>(w[i][1]);
    }
    const float pn = lane_xor16<M>(nrm);

    v2f d0 = w[0]*pw[0], d1 = w[1]*pw[1];
    #pragma unroll
    for (int i = 2; i < 8; i += 2) {
        d0 = __builtin_elementwise_fma(w[i],   pw[i],   d0);
        d1 = __builtin_elementwise_fma(w[i+1], pw[i+1], d1);
    }
    const v2f ds = d0 + d1;
    const float gam = ds[0] + ds[1];

    const bool  low = ((j ^ M) > j);        // canonical order -> identical c,s
    const float na  = low ? nrm : pn;
    const float nb  = low ? pn  : nrm;

    const float thr = 1e-12f * (na + nb);
    const bool  rot = fabsf(gam) > thr;
    const float gs  = rot ? gam : 1.f;
    const float zeta = (nb - na) * (0.5f * __builtin_amdgcn_rcpf(gs));
    const float rt   = __builtin_amdgcn_rcpf(
                           fabsf(zeta) +
                           __builtin_amdgcn_sqrtf(__builtin_fmaf(zeta, zeta, 1.f)));
    float t  = copysignf(rt, zeta);
    float c  = __builtin_amdgcn_rsqf(__builtin_fmaf(t, t, 1.f));
    float sv = c * t;
    if (!rot) { c = 1.f; sv = 0.f; t = 0.f; }

    const float ss = low ? -sv : sv;
    const v2f c2 = {c, c}, sp = {ss, ss};
    #pragma unroll
    for (int i = 0; i < 8; ++i)
        w[i] = __builtin_elementwise_fma(c2, w[i], sp*pw[i]);

    // Rutishauser: norm update at the zeroing rotation.
    nrm = __builtin_fmaf(low ? -t : t, gam, nrm);
}

// Shared phases 1-4: Gram (MFMA) + Jacobi + Phi (MFMA; Phi left in Gl).
// One wave, 4 matrices, 16 lanes/matrix. No block barriers.
__device__ __forceinline__ void gram_jacobi_phi(
        const float* __restrict__ x, const int wid, const int warp,
        const int lane, float Gl[4][4][320]) {
    const int g   = lane >> 4;
    const int j   = lane & 15;
    const int kq4 = g * 4;

    // -------- Phase 1: Gram via MFMA (no LDS, no barriers) ------------------
    // lane = (channel j, k-block g): loads channel j, block rows g and g+4,
    // all 8 cols -> A-frag == B-frag of G = M^T M.
    // MFMA results consumed ONLY by plain stores (hard rule b).
    #pragma unroll
    for (int s = 0; s < 4; ++s) {
        const int id  = wid * 4 + s;
        const int n   = id / NBB_;
        const int rem = id % NBB_;
        const int bi  = rem / NB_;
        const int bj  = rem % NB_;
        const float* bp = x + (size_t)n * (A_ * PLANE_) + (size_t)j * PLANE_
                            + (bi*4 + g) * W_ + bj*4;

        const float4 va = *(const float4*)(bp);
        const float4 vb = *(const float4*)(bp + 4);
        const float4 vc = *(const float4*)(bp + 4*W_);
        const float4 vd = *(const float4*)(bp + 4*W_ + 4);

        frag8 hi0, lo0, hi1, lo1;
        split8(va, vb, hi0, lo0);
        split8(vc, vd, hi1, lo1);

        f32x4 C = {0.f, 0.f, 0.f, 0.f};
        C = __builtin_amdgcn_mfma_f32_16x16x32_bf16(lo0.s8, hi0.s8, C, 0, 0, 0);
        C = __builtin_amdgcn_mfma_f32_16x16x32_bf16(hi0.s8, lo0.s8, C, 0, 0, 0);
        C = __builtin_amdgcn_mfma_f32_16x16x32_bf16(hi0.s8, hi0.s8, C, 0, 0, 0);
        C = __builtin_amdgcn_mfma_f32_16x16x32_bf16(lo1.s8, hi1.s8, C, 0, 0, 0);
        C = __builtin_amdgcn_mfma_f32_16x16x32_bf16(hi1.s8, lo1.s8, C, 0, 0, 0);
        C = __builtin_amdgcn_mfma_f32_16x16x32_bf16(hi1.s8, hi1.s8, C, 0, 0, 0);

        // C lane layout: col=lane&15 (=j), row=4*(lane>>4)+r (=kq4+r):
        // exactly the per-lane Gram output layout.
        *(float4*)&Gl[warp][s][j*20 + kq4] = make_float4(C[0], C[1], C[2], C[3]);
    }
    __builtin_amdgcn_wave_barrier();

    // -------- Phase 2: my column into registers -----------------------------
    v2f w[8];
    {
        f4v2 t0, t1, t2, t3;
        t0.f4 = *(const float4*)&Gl[warp][g][j*20 + 0];
        t1.f4 = *(const float4*)&Gl[warp][g][j*20 + 4];
        t2.f4 = *(const float4*)&Gl[warp][g][j*20 + 8];
        t3.f4 = *(const float4*)&Gl[warp][g][j*20 + 12];
        w[0]=t0.v2[0]; w[1]=t0.v2[1]; w[2]=t1.v2[0]; w[3]=t1.v2[1];
        w[4]=t2.v2[0]; w[5]=t2.v2[1]; w[6]=t3.v2[0]; w[7]=t3.v2[1];
    }
    float nrm;
    {
        v2f d = pk_mul(w[0], w[0]);
        #pragma unroll
        for (int i = 1; i < 8; ++i) d = pk_fma(w[i], w[i], d);
        nrm = d[0] + d[1];
    }

    // -------- Phase 3: one-sided Jacobi (4 sweeps REQUIRED, R14) ------------
    for (int sweep = 0; sweep < NSWEEP_; ++sweep) {
        jacobi_round<1>(w, nrm, j);  jacobi_round<2>(w, nrm, j);
        jacobi_round<3>(w, nrm, j);  jacobi_round<4>(w, nrm, j);
        jacobi_round<5>(w, nrm, j);  jacobi_round<6>(w, nrm, j);
        jacobi_round<7>(w, nrm, j);  jacobi_round<8>(w, nrm, j);
        jacobi_round<9>(w, nrm, j);  jacobi_round<10>(w, nrm, j);
        jacobi_round<11>(w, nrm, j); jacobi_round<12>(w, nrm, j);
        jacobi_round<13>(w, nrm, j); jacobi_round<14>(w, nrm, j);
        jacobi_round<15>(w, nrm, j);
    }
    {   // exact norm (drift removal)
        v2f d = pk_mul(w[0], w[0]);
        #pragma unroll
        for (int i = 1; i < 8; ++i) d = pk_fma(w[i], w[i], d);
        nrm = d[0] + d[1];
    }
    float rho = 0.f;                         // max(1-2/sigma,0)/lam^2
    if (nrm > 16.f) {
        const float lam = __builtin_amdgcn_sqrtf(nrm);
        rho = (1.f - 2.f * __builtin_amdgcn_rsqf(lam)) * __builtin_amdgcn_rcpf(nrm);
    }

    __builtin_amdgcn_wave_barrier();
    *(float4*)&Gl[warp][g][j*20 + 0]  = make_float4(w[0][0], w[0][1], w[1][0], w[1][1]);
    *(float4*)&Gl[warp][g][j*20 + 4]  = make_float4(w[2][0], w[2][1], w[3][0], w[3][1]);
    *(float4*)&Gl[warp][g][j*20 + 8]  = make_float4(w[4][0], w[4][1], w[5][0], w[5][1]);
    *(float4*)&Gl[warp][g][j*20 + 12] = make_float4(w[6][0], w[6][1], w[7][0], w[7][1]);
    Gl[warp][g][j*20 + 16] = rho;
    __builtin_amdgcn_wave_barrier();

    // -------- Phase 4 (MFMA): Phi_s = (rho (.) W) W^T, K=16 padded to 32 ----
    // lane&15 = Phi row i (A) = Phi col j (B): the same LDS reads build both
    // fragments. kgroups (lane>>4) 0,1 carry k=0..15; 2,3 supply zeros.
    // bf16 hi/lo on both operands, drop lo*lo. MFMA dest -> plain stores.
    {
        const int kg = lane >> 4;
        const int mn = lane & 15;
        f32x4 PhiC[4];
        #pragma unroll
        for (int s = 0; s < 4; ++s) {
            frag8 Ahi, Alo, Bhi, Blo;
            if (kg < 2) {
                float av[8], bv[8];
                #pragma unroll
                for (int e = 0; e < 8; ++e) {
                    const int k = kg*8 + e;
                    const float wv = Gl[warp][s][k*20 + mn];
                    const float rh = Gl[warp][s][k*20 + 16];
                    bv[e] = wv;
                    av[e] = wv * rh;
                }
                split8(make_float4(av[0],av[1],av[2],av[3]),
                       make_float4(av[4],av[5],av[6],av[7]), Ahi, Alo);
                split8(make_float4(bv[0],bv[1],bv[2],bv[3]),
                       make_float4(bv[4],bv[5],bv[6],bv[7]), Bhi, Blo);
            } else {
                Ahi.u[0]=0u; Ahi.u[1]=0u; Ahi.u[2]=0u; Ahi.u[3]=0u;
                Alo = Ahi; Bhi = Ahi; Blo = Ahi;
            }
            f32x4 C = {0.f, 0.f, 0.f, 0.f};
            C = __builtin_amdgcn_mfma_f32_16x16x32_bf16(Alo.s8, Bhi.s8, C, 0, 0, 0);
            C = __builtin_amdgcn_mfma_f32_16x16x32_bf16(Ahi.s8, Blo.s8, C, 0, 0, 0);
            C = __builtin_amdgcn_mfma_f32_16x16x32_bf16(Ahi.s8, Bhi.s8, C, 0, 0, 0);
            PhiC[s] = C;
        }
        __builtin_amdgcn_wave_barrier();      // all W/rho reads done -> overwrite
        #pragma unroll
        for (int s = 0; s < 4; ++s) {
            #pragma unroll
            for (int r2 = 0; r2 < 4; ++r2)
                Gl[warp][s][(4*kg + r2)*20 + mn] = PhiC[s][r2];
        }
        __builtin_amdgcn_wave_barrier();
    }
}

// =================== K1: Phi per block -> global ============================
__global__ __launch_bounds__(256, 8)
void llr_phi(const float* __restrict__ x, float* __restrict__ phiG) {
    __shared__ __align__(16) float Gl[4][4][320];   // 20480 B -> 8 blocks/CU
    const int warp = threadIdx.x >> 6;
    const int lane = threadIdx.x & 63;

    // bijective XCD-chunked swizzle: nwg=2257, q=282, r=1.
    const int xcd = blockIdx.x & 7, idx = blockIdx.x >> 3;
    const int wg  = (xcd == 0 ? idx : 283 + (xcd - 1) * 282 + idx);
    const int wid = wg * 4 + warp;
    if (wid >= NWAVE_) return;

    gram_jacobi_phi(x, wid, warp, lane, Gl);

    // Phi symmetric -> column j IS row j: 64B contiguous store per lane.
    const int g = lane >> 4, j = lane & 15;
    float* pb = phiG + (size_t)(wid*4 + g) * 256 + j * 16;
    const float4 p0 = *(const float4*)&Gl[warp][g][j*20 + 0];
    const float4 p1 = *(const float4*)&Gl[warp][g][j*20 + 4];
    const float4 p2 = *(const float4*)&Gl[warp][g][j*20 + 8];
    const float4 p3 = *(const float4*)&Gl[warp][g][j*20 + 12];
    *(float4*)&pb[0]  = p0;  *(float4*)&pb[4]  = p1;
    *(float4*)&pb[8]  = p2;  *(float4*)&pb[12] = p3;
}

// =================== K2: out = x * (sum Phi)/w, tiled 8x32 px ===============
__global__ __launch_bounds__(256, 8)
void llr_out2(const float* __restrict__ x, const float* __restrict__ phiG,
              float* __restrict__ out) {
    __shared__ __align__(16) float Sl[16][260];   // stride 260: conflict-free reads

    // bijective XCD-chunked swizzle: nwg=2304 (divisible by 8), q=288.
    const int b  = (blockIdx.x & 7) * 288 + (blockIdx.x >> 3);
    const int n  = b / 576;
    const int tt = b % 576;
    const int tr = tt / 12, tc = tt % 12;
    const int r0 = tr*8, c0 = tc*32;
    const int cr0 = tr*2, cc0 = tc*8;   // global cell coords of tile origin

    const int r = threadIdx.x >> 5;          // 0..7 (wave = 2 rows, same cell-row)
    const int c = threadIdx.x & 31;          // 0..31 -> coalesced
    const int lcc = ((r >> 2) << 3) + (c >> 2);
    const size_t sb = (size_t)n * (A_*PLANE_) + (size_t)(r0 + r) * W_ + (c0 + c);

    // -------- stage S FIRST (critical-path gather issued first, rule d): ----
    // branch-free clamped 4-load sum * 0.25 (== weighted sum exactly).
    {
        const int lc = threadIdx.x >> 4;         // local cell 0..15
        const int fo = (threadIdx.x & 15) * 4;   // float offset 0..60
        const int ci = cr0 + (lc >> 3);
        const int cj = cc0 + (lc & 7);
        const int bi0 = max(ci - 1, 0), bi1 = min(ci, NB_ - 1);
        const int bj0 = max(cj - 1, 0), bj1 = min(cj, NB_ - 1);
        const size_t r00 = ((size_t)(n*NBB_ + bi0*NB_ + bj0))*256;
        const size_t r01 = ((size_t)(n*NBB_ + bi0*NB_ + bj1))*256;
        const size_t r10 = ((size_t)(n*NBB_ + bi1*NB_ + bj0))*256;
        const size_t r11 = ((size_t)(n*NBB_ + bi1*NB_ + bj1))*256;
        #pragma unroll
        for (int it = 0; it < 4; ++it) {
            const int off = fo + it*64;
            const float4 a  = *(const float4*)&phiG[r00 + off];
            const float4 bq = *(const float4*)&phiG[r01 + off];
            const float4 cq = *(const float4*)&phiG[r10 + off];
            const float4 d  = *(const float4*)&phiG[r11 + off];
            float4 s;
            s.x = (a.x + bq.x + cq.x + d.x) * 0.25f;
            s.y = (a.y + bq.y + cq.y + d.y) * 0.25f;
            s.z = (a.z + bq.z + cq.z + d.z) * 0.25f;
            s.w = (a.w + bq.w + cq.w + d.w) * 0.25f;
            *(float4*)&Sl[lc][off] = s;
        }
    }

    // -------- x loads: issued AFTER the gather (already in flight), BEFORE
    // the barrier -- their latency hides under the barrier wait. ------------
    float xk[16];
    #pragma unroll
    for (int k = 0; k < 16; ++k) xk[k] = x[sb + (size_t)k * PLANE_];

    __syncthreads();

    // -------- compute: thread = 1 pixel, all 16 channels --------------------
    v2f acc[8];
    #pragma unroll
    for (int i = 0; i < 8; ++i) acc[i] = (v2f){0.f, 0.f};
    #pragma unroll
    for (int k = 0; k < 16; ++k) {
        const v2f xv = {xk[k], xk[k]};
        f4v2 s0, s1, s2, s3;
        s0.f4 = *(const float4*)&Sl[lcc][k*16 + 0];
        s1.f4 = *(const float4*)&Sl[lcc][k*16 + 4];
        s2.f4 = *(const float4*)&Sl[lcc][k*16 + 8];
        s3.f4 = *(const float4*)&Sl[lcc][k*16 + 12];
        acc[0] = pk_fma(xv, s0.v2[0], acc[0]);
        acc[1] = pk_fma(xv, s0.v2[1], acc[1]);
        acc[2] = pk_fma(xv, s1.v2[0], acc[2]);
        acc[3] = pk_fma(xv, s1.v2[1], acc[3]);
        acc[4] = pk_fma(xv, s2.v2[0], acc[4]);
        acc[5] = pk_fma(xv, s2.v2[1], acc[5]);
        acc[6] = pk_fma(xv, s3.v2[0], acc[6]);
        acc[7] = pk_fma(xv, s3.v2[1], acc[7]);
    }
    #pragma unroll
    for (int i = 0; i < 8; ++i) {
        out[sb + (size_t)(2*i)     * PLANE_] = acc[i][0];
        out[sb + (size_t)(2*i + 1) * PLANE_] = acc[i][1];
    }
}

// =================== Fallback (ws too small): fused + atomics ===============
__global__ __launch_bounds__(256, 5)
void llr_fused(const float* __restrict__ x, float* __restrict__ out) {
    __shared__ __align__(16) float Gl[4][4][320];
    const int warp = threadIdx.x >> 6;
    const int lane = threadIdx.x & 63;
    const int wid  = blockIdx.x * 4 + warp;
    if (wid >= NWAVE_) return;

    gram_jacobi_phi(x, wid, warp, lane, Gl);

    const int pr = lane >> 3, pc = lane & 7;
    for (int s = 0; s < 4; ++s) {
        const int id = wid*4 + s;
        const int n = id / NBB_, rem = id % NBB_;
        const int bi = rem / NB_, bj = rem % NB_;
        const int base = n*(A_*PLANE_) + (bi*4+pr)*W_ + (bj*4+pc);
        float mr[16];
        #pragma unroll
        for (int a = 0; a < 16; ++a) mr[a] = x[base + a*PLANE_];
        float o[16];
        #pragma unroll
        for (int a = 0; a < 16; ++a) o[a] = 0.f;
        #pragma unroll
        for (int k = 0; k < 16; ++k) {
            const float mk = mr[k];
            const float4 f0 = *(const float4*)&Gl[warp][s][k*20 + 0];
            const float4 f1 = *(const float4*)&Gl[warp][s][k*20 + 4];
            const float4 f2 = *(const float4*)&Gl[warp][s][k*20 + 8];
            const float4 f3 = *(const float4*)&Gl[warp][s][k*20 + 12];
            o[0]+=mk*f0.x;  o[1]+=mk*f0.y;  o[2]+=mk*f0.z;  o[3]+=mk*f0.w;
            o[4]+=mk*f1.x;  o[5]+=mk*f1.y;  o[6]+=mk*f1.z;  o[7]+=mk*f1.w;
            o[8]+=mk*f2.x;  o[9]+=mk*f2.y;  o[10]+=mk*f2.z; o[11]+=mk*f2.w;
            o[12]+=mk*f3.x; o[13]+=mk*f3.y; o[14]+=mk*f3.z; o[15]+=mk*f3.w;
        }
        #pragma unroll
        for (int a = 0; a < 16; ++a)
            unsafeAtomicAdd(&out[base + a*PLANE_], o[a]);
    }
}

__global__ __launch_bounds__(256)
void llr_div(float* __restrict__ out, const float* __restrict__ bw) {
    const int i = (blockIdx.x * 256 + threadIdx.x) * 4;
    float4 o = *(float4*)&out[i];
    const float4 bv = *(const float4*)&bw[i % PLANE_];
    o.x /= bv.x; o.y /= bv.y; o.z /= bv.z; o.w /= bv.w;
    *(float4*)&out[i] = o;
}

extern "C" void kernel_launch(void* const* d_in, const int* in_sizes, int n_in,
                              void* d_out, int out_size, void* d_ws, size_t ws_size,
                              hipStream_t stream) {
    (void)in_sizes; (void)n_in;
    const float* x  = (const float*)d_in[0];
    const float* bw = (const float*)d_in[1];
    float* out = (float*)d_out;

    if (ws_size >= PHI_BYTES_) {
        float* phiG = (float*)d_ws;
        hipLaunchKernelGGL(llr_phi,  dim3((NWAVE_ + 3) / 4), dim3(256), 0, stream, x, phiG);
        hipLaunchKernelGGL(llr_out2, dim3(4 * 48 * 12),      dim3(256), 0, stream, x, phiG, out);
    } else {
        hipMemsetAsync(out, 0, (size_t)out_size * sizeof(float), stream);
        hipLaunchKernelGGL(llr_fused, dim3((NWAVE_ + 3) / 4), dim3(256), 0, stream, x, out);
        hipLaunchKernelGGL(llr_div, dim3((N_*A_*PLANE_) / (256*4)), dim3(256), 0, stream, out, bw);
    }
}